// Round 4
// baseline (4130.750 us; speedup 1.0000x reference)
//
#include <hip/hip_runtime.h>
#include <hip/hip_bf16.h>

#define NGRAPH 64
#define NGENES 16000
#define NANNOT 8000
#define NNODES 10000
#define NTOT   (NGRAPH * NNODES)
#define DEG    4
#define NEDGE  (NGRAPH * NNODES * DEG)
#define KSEL   5000
#define FIXS   1048576.0f   // 2^20 fixed-point scale for deterministic aggregation

// ---------------- kernel A: init xg = bias (annot region) / x (rest) ----------------
__global__ void init_xg_kernel(const float* __restrict__ x,
                               const float* __restrict__ fc1_b,
                               float* __restrict__ xg) {
  int n = blockIdx.x * blockDim.x + threadIdx.x;
  if (n >= NTOT) return;
  int local = n % NNODES;
  xg[n] = (local < NANNOT) ? fc1_b[local] : x[n];
}

// ---------------- kernel B: masked fc1 GEMM, fp32 VALU, 8x8 reg tile ----------------
// emb[64 x 8000] = trans[64 x 16000] * (w .* mask)^T
#define KC     40
#define ATILE  256
#define KSPLIT 16
#define PITCH  44

template <int DET>
__global__ __launch_bounds__(256, 2) void fc1_kernel(
    const float* __restrict__ tr, const float* __restrict__ w,
    const float* __restrict__ mk, float* __restrict__ xg,
    float* __restrict__ partials) {
  __shared__ float Tl[64 * PITCH];
  __shared__ float Wl[ATILE * PITCH];
  const int t = threadIdx.x;
  const int abase = blockIdx.x * ATILE;
  const int kbeg = blockIdx.y * (NGENES / KSPLIT);

  float acc[8][8];
#pragma unroll
  for (int i = 0; i < 8; ++i)
#pragma unroll
    for (int j = 0; j < 8; ++j) acc[i][j] = 0.f;

  const int tb = t >> 5;   // 0..7
  const int ta = t & 31;   // 0..31

#pragma unroll 1
  for (int c = 0; c < (NGENES / KSPLIT) / KC; ++c) {
    const int k0 = kbeg + c * KC;
    for (int idx = t; idx < 64 * (KC / 4); idx += 256) {
      int row = idx / (KC / 4), q = idx % (KC / 4);
      float4 v = *(const float4*)&tr[row * NGENES + k0 + q * 4];
      *(float4*)&Tl[row * PITCH + q * 4] = v;
    }
    for (int idx = t; idx < ATILE * (KC / 4); idx += 256) {
      int row = idx / (KC / 4), q = idx % (KC / 4);
      int a = abase + row;
      float4 pv = make_float4(0.f, 0.f, 0.f, 0.f);
      if (a < NANNOT) {
        size_t off = (size_t)a * NGENES + k0 + q * 4;
        float4 wv = *(const float4*)&w[off];
        float4 mv = *(const float4*)&mk[off];
        pv = make_float4(wv.x * mv.x, wv.y * mv.y, wv.z * mv.z, wv.w * mv.w);
      }
      *(float4*)&Wl[row * PITCH + q * 4] = pv;
    }
    __syncthreads();
#pragma unroll
    for (int kk = 0; kk < KC / 4; ++kk) {
      float4 tv[8], wv[8];
#pragma unroll
      for (int i = 0; i < 8; ++i) tv[i] = *(const float4*)&Tl[(tb + 8 * i) * PITCH + kk * 4];
#pragma unroll
      for (int j = 0; j < 8; ++j) wv[j] = *(const float4*)&Wl[(ta + 32 * j) * PITCH + kk * 4];
#pragma unroll
      for (int i = 0; i < 8; ++i)
#pragma unroll
        for (int j = 0; j < 8; ++j)
          acc[i][j] += tv[i].x * wv[j].x + tv[i].y * wv[j].y +
                       tv[i].z * wv[j].z + tv[i].w * wv[j].w;
    }
    __syncthreads();
  }
  if (DET) {
    float* P = partials + (size_t)blockIdx.y * (64 * NANNOT);
#pragma unroll
    for (int i = 0; i < 8; ++i) {
      int b = tb + 8 * i;
#pragma unroll
      for (int j = 0; j < 8; ++j) {
        int a = abase + ta + 32 * j;
        if (a < NANNOT) P[b * NANNOT + a] = acc[i][j];
      }
    }
  } else {
#pragma unroll
    for (int i = 0; i < 8; ++i) {
      int b = tb + 8 * i;
#pragma unroll
      for (int j = 0; j < 8; ++j) {
        int a = abase + ta + 32 * j;
        if (a < NANNOT) atomicAdd(&xg[(size_t)b * NNODES + a], acc[i][j]);
      }
    }
  }
}

// ---------------- kernel B2: deterministic reduce of k-split partials ---------------
__global__ void reduce_kernel(const float* __restrict__ partials,
                              const float* __restrict__ fc1_b,
                              float* __restrict__ xg) {
  int idx = blockIdx.x * blockDim.x + threadIdx.x;
  if (idx >= 64 * NANNOT) return;
  int b = idx / NANNOT, a = idx % NANNOT;
  float s = fc1_b[a];
#pragma unroll
  for (int sp = 0; sp < KSPLIT; ++sp) s += partials[(size_t)sp * (64 * NANNOT) + idx];
  xg[(size_t)b * NNODES + a] = s;
}

// ---------------- kernel C: fused graph-conv + top-k select + fc2 ------------------
// LDS budget: 3*40000 + 1024 + 4096 + 4096 + 8 = 129224 B < 163840 B
__global__ __launch_bounds__(1024) void graph_kernel(
    const int* __restrict__ ei, const float* __restrict__ xg,
    const float* __restrict__ wrp, const float* __restrict__ wnp,
    const float* __restrict__ pbp, const float* __restrict__ fc2w,
    const float* __restrict__ fc2b, float* __restrict__ out) {
  const int g = blockIdx.x;
  const int t = threadIdx.x;
  __shared__ int   s_sum[NNODES];   // fixed-point msg sum (x 2^20), deterministic
  __shared__ int   s_deg[NNODES];   // in-degree
  __shared__ float s_h[NNODES];     // h values (key = fabsf(h) on the fly)
  __shared__ int s_hist[256];
  __shared__ int s_cnt[1024];
  __shared__ float s_red[1024];
  __shared__ unsigned s_pfx;
  __shared__ int s_rem;

  for (int i = t; i < NNODES; i += 1024) { s_sum[i] = 0; s_deg[i] = 0; }
  __syncthreads();

  const int e0 = g * (NNODES * DEG);
  const int base = g * NNODES;
  for (int e = t; e < NNODES * DEG; e += 1024) {
    int s = ei[e0 + e];
    int d = ei[NEDGE + e0 + e];
    float v = ((unsigned)s < (unsigned)NTOT) ? xg[s] : 0.f;
    unsigned dl = (unsigned)(d - base);
    if (dl < (unsigned)NNODES) {
      atomicAdd(&s_sum[dl], __float2int_rn(v * FIXS));
      atomicAdd(&s_deg[dl], 1);
    }
  }
  __syncthreads();

  const float wr = wrp[0], wn = wnp[0], pb = pbp[0];
  for (int i = t; i < NNODES; i += 1024) {
    int dg = s_deg[i];
    float mean = ((float)s_sum[i] * (1.0f / FIXS)) / (float)(dg > 0 ? dg : 1);
    float h = wr * xg[base + i] + wn * mean + pb;
    s_h[i] = h;
  }
  __syncthreads();

  // radix-select the KSEL-th largest |h| (exact, MSB-first 8-bit digits)
  unsigned prefix = 0; int rem = KSEL;
  for (int byte = 3; byte >= 0; --byte) {
    const int sh = byte * 8;
    const unsigned himask = (byte == 3) ? 0u : (0xFFFFFFFFu << (sh + 8));
    for (int i = t; i < 256; i += 1024) s_hist[i] = 0;
    __syncthreads();
    for (int i = t; i < NNODES; i += 1024) {
      unsigned kk = __float_as_uint(fabsf(s_h[i]));
      if ((kk & himask) == prefix) atomicAdd(&s_hist[(kk >> sh) & 255], 1);
    }
    __syncthreads();
    if (t == 0) {
      int cum = 0, d = 255;
      for (; d >= 0; --d) {
        int c = s_hist[d];
        if (cum + c >= rem) break;
        cum += c;
      }
      if (d < 0) d = 0;
      s_pfx = prefix | ((unsigned)d << sh);
      s_rem = rem - cum;
    }
    __syncthreads();
    prefix = s_pfx; rem = s_rem;
    __syncthreads();
  }
  const unsigned T = prefix;
  const int needed = rem;

  // prefix-rank over ==T elements (lowest-index tie-break, matches jax top_k)
  const int CH = 10;
  int i0 = t * CH;
  int i1 = i0 + CH; if (i1 > NNODES) i1 = NNODES;
  int loc = 0;
  for (int i = i0; i < i1; ++i)
    loc += (__float_as_uint(fabsf(s_h[i])) == T) ? 1 : 0;
  s_cnt[t] = loc;
  __syncthreads();
  for (int off = 1; off < 1024; off <<= 1) {
    int v = (t >= off) ? s_cnt[t - off] : 0;
    __syncthreads();
    s_cnt[t] += v;
    __syncthreads();
  }
  int rank = s_cnt[t] - loc;

  float a0 = 0.f, a1 = 0.f;
  for (int i = i0; i < i1; ++i) {
    float h = s_h[i];
    unsigned kk = __float_as_uint(fabsf(h));
    bool inc = false;
    if (kk > T) inc = true;
    else if (kk == T) { inc = (rank < needed); ++rank; }
    if (inc) {
      a0 += h * fc2w[i];
      a1 += h * fc2w[NNODES + i];
    }
  }
  s_red[t] = a0; __syncthreads();
  for (int off = 512; off > 0; off >>= 1) {
    if (t < off) s_red[t] += s_red[t + off];
    __syncthreads();
  }
  float r0 = s_red[0];
  __syncthreads();
  s_red[t] = a1; __syncthreads();
  for (int off = 512; off > 0; off >>= 1) {
    if (t < off) s_red[t] += s_red[t + off];
    __syncthreads();
  }
  if (t == 0) {
    out[g * 2 + 0] = r0 + fc2b[0];
    out[g * 2 + 1] = s_red[0] + fc2b[1];
  }
}

// ---------------- launch ----------------
extern "C" void kernel_launch(void* const* d_in, const int* in_sizes, int n_in,
                              void* d_out, int out_size, void* d_ws, size_t ws_size,
                              hipStream_t stream) {
  const float* tr  = (const float*)d_in[0];
  const float* x   = (const float*)d_in[1];
  const int*   ei  = (const int*)d_in[2];
  const float* adj = (const float*)d_in[4];
  const float* w1  = (const float*)d_in[5];
  const float* b1  = (const float*)d_in[6];
  const float* wr  = (const float*)d_in[7];
  const float* wn  = (const float*)d_in[8];
  const float* pb  = (const float*)d_in[9];
  const float* w2  = (const float*)d_in[10];
  const float* b2  = (const float*)d_in[11];

  char* ws = (char*)d_ws;
  float* xg = (float*)ws;                                   // 2.56 MB
  float* partials = (float*)(ws + (size_t)NTOT * 4 + 256);  // 32.8 MB
  size_t need = (size_t)NTOT * 4 + 256 + (size_t)KSPLIT * 64 * NANNOT * 4;
  const bool det = ws_size >= need;

  float* out = (float*)d_out;

  init_xg_kernel<<<(NTOT + 255) / 256, 256, 0, stream>>>(x, b1, xg);
  dim3 g1((NANNOT + ATILE - 1) / ATILE, KSPLIT);
  if (det) {
    fc1_kernel<1><<<g1, 256, 0, stream>>>(tr, w1, adj, xg, partials);
    reduce_kernel<<<(64 * NANNOT + 255) / 256, 256, 0, stream>>>(partials, b1, xg);
  } else {
    fc1_kernel<0><<<g1, 256, 0, stream>>>(tr, w1, adj, xg, partials);
  }
  graph_kernel<<<NGRAPH, 1024, 0, stream>>>(ei, xg, wr, wn, pb, w2, b2, out);
}

// Round 5
// 494.338 us; speedup vs baseline: 8.3561x; 8.3561x over previous
//
#include <hip/hip_runtime.h>
#include <hip/hip_bf16.h>

#define NGRAPH 64
#define NGENES 16000
#define NANNOT 8000
#define NNODES 10000
#define NTOT   (NGRAPH * NNODES)
#define DEG    4
#define NEDGE  (NGRAPH * NNODES * DEG)
#define KSEL   5000
#define FIXS   1048576.0f   // 2^20 fixed-point scale for deterministic aggregation

// ---------------- kernel A: init xg = bias (annot region) / x (rest) ----------------
__global__ void init_xg_kernel(const float* __restrict__ x,
                               const float* __restrict__ fc1_b,
                               float* __restrict__ xg) {
  int n = blockIdx.x * blockDim.x + threadIdx.x;
  if (n >= NTOT) return;
  int local = n % NNODES;
  xg[n] = (local < NANNOT) ? fc1_b[local] : x[n];
}

// ---------------- kernel B: masked fc1 GEMM, fp32 VALU, 8x8 reg tile ----------------
// emb[64 x 8000] = trans[64 x 16000] * (w .* mask)^T
#define KC     40
#define ATILE  256
#define KSPLIT 16
#define PITCH  44

template <int DET>
__global__ __launch_bounds__(256, 1) void fc1_kernel(
    const float* __restrict__ tr, const float* __restrict__ w,
    const float* __restrict__ mk, float* __restrict__ xg,
    float* __restrict__ partials) {
  __shared__ float Tl[64 * PITCH];
  __shared__ float Wl[ATILE * PITCH];
  const int t = threadIdx.x;
  const int abase = blockIdx.x * ATILE;
  const int kbeg = blockIdx.y * (NGENES / KSPLIT);

  float acc[8][8];
#pragma unroll
  for (int i = 0; i < 8; ++i)
#pragma unroll
    for (int j = 0; j < 8; ++j) acc[i][j] = 0.f;

  const int tb = t >> 5;   // 0..7
  const int ta = t & 31;   // 0..31

#pragma unroll 1
  for (int c = 0; c < (NGENES / KSPLIT) / KC; ++c) {   // 25 chunks
    const int k0 = kbeg + c * KC;
    for (int idx = t; idx < 64 * (KC / 4); idx += 256) {
      int row = idx / (KC / 4), q = idx % (KC / 4);
      float4 v = *(const float4*)&tr[row * NGENES + k0 + q * 4];
      *(float4*)&Tl[row * PITCH + q * 4] = v;
    }
    for (int idx = t; idx < ATILE * (KC / 4); idx += 256) {
      int row = idx / (KC / 4), q = idx % (KC / 4);
      int a = abase + row;
      float4 pv = make_float4(0.f, 0.f, 0.f, 0.f);
      if (a < NANNOT) {
        size_t off = (size_t)a * NGENES + k0 + q * 4;
        float4 wv = *(const float4*)&w[off];
        float4 mv = *(const float4*)&mk[off];
        pv = make_float4(wv.x * mv.x, wv.y * mv.y, wv.z * mv.z, wv.w * mv.w);
      }
      *(float4*)&Wl[row * PITCH + q * 4] = pv;
    }
    __syncthreads();
    // inner loop: keep live set ~100 VGPR (acc 64 + wv 32 + tv 4); unroll 1
    // on kk prevents cross-iteration load hoisting (the round-4 spill cause)
#pragma unroll 1
    for (int kk = 0; kk < KC / 4; ++kk) {
      float4 wv[8];
#pragma unroll
      for (int j = 0; j < 8; ++j)
        wv[j] = *(const float4*)&Wl[(ta + 32 * j) * PITCH + kk * 4];
#pragma unroll
      for (int i = 0; i < 8; ++i) {
        float4 tv = *(const float4*)&Tl[(tb + 8 * i) * PITCH + kk * 4];
#pragma unroll
        for (int j = 0; j < 8; ++j)
          acc[i][j] += tv.x * wv[j].x + tv.y * wv[j].y +
                       tv.z * wv[j].z + tv.w * wv[j].w;
      }
    }
    __syncthreads();
  }
  if (DET) {
    float* P = partials + (size_t)blockIdx.y * (64 * NANNOT);
#pragma unroll
    for (int i = 0; i < 8; ++i) {
      int b = tb + 8 * i;
#pragma unroll
      for (int j = 0; j < 8; ++j) {
        int a = abase + ta + 32 * j;
        if (a < NANNOT) P[b * NANNOT + a] = acc[i][j];
      }
    }
  } else {
#pragma unroll
    for (int i = 0; i < 8; ++i) {
      int b = tb + 8 * i;
#pragma unroll
      for (int j = 0; j < 8; ++j) {
        int a = abase + ta + 32 * j;
        if (a < NANNOT) atomicAdd(&xg[(size_t)b * NNODES + a], acc[i][j]);
      }
    }
  }
}

// ---------------- kernel B2: deterministic reduce of k-split partials ---------------
__global__ void reduce_kernel(const float* __restrict__ partials,
                              const float* __restrict__ fc1_b,
                              float* __restrict__ xg) {
  int idx = blockIdx.x * blockDim.x + threadIdx.x;
  if (idx >= 64 * NANNOT) return;
  int b = idx / NANNOT, a = idx % NANNOT;
  float s = fc1_b[a];
#pragma unroll
  for (int sp = 0; sp < KSPLIT; ++sp) s += partials[(size_t)sp * (64 * NANNOT) + idx];
  xg[(size_t)b * NNODES + a] = s;
}

// ---------------- kernel C: fused graph-conv + top-k select + fc2 ------------------
// LDS budget: 3*40000 + 1024 + 4096 + 4096 + 8 = 129224 B < 163840 B
__global__ __launch_bounds__(1024) void graph_kernel(
    const int* __restrict__ ei, const float* __restrict__ xg,
    const float* __restrict__ wrp, const float* __restrict__ wnp,
    const float* __restrict__ pbp, const float* __restrict__ fc2w,
    const float* __restrict__ fc2b, float* __restrict__ out) {
  const int g = blockIdx.x;
  const int t = threadIdx.x;
  __shared__ int   s_sum[NNODES];   // fixed-point msg sum (x 2^20), deterministic
  __shared__ int   s_deg[NNODES];   // in-degree
  __shared__ float s_h[NNODES];     // h values (key = fabsf(h) on the fly)
  __shared__ int s_hist[256];
  __shared__ int s_cnt[1024];
  __shared__ float s_red[1024];
  __shared__ unsigned s_pfx;
  __shared__ int s_rem;

  for (int i = t; i < NNODES; i += 1024) { s_sum[i] = 0; s_deg[i] = 0; }
  __syncthreads();

  const int e0 = g * (NNODES * DEG);
  const int base = g * NNODES;
  for (int e = t; e < NNODES * DEG; e += 1024) {
    int s = ei[e0 + e];
    int d = ei[NEDGE + e0 + e];
    float v = ((unsigned)s < (unsigned)NTOT) ? xg[s] : 0.f;
    unsigned dl = (unsigned)(d - base);
    if (dl < (unsigned)NNODES) {
      atomicAdd(&s_sum[dl], __float2int_rn(v * FIXS));
      atomicAdd(&s_deg[dl], 1);
    }
  }
  __syncthreads();

  const float wr = wrp[0], wn = wnp[0], pb = pbp[0];
  for (int i = t; i < NNODES; i += 1024) {
    int dg = s_deg[i];
    float mean = ((float)s_sum[i] * (1.0f / FIXS)) / (float)(dg > 0 ? dg : 1);
    float h = wr * xg[base + i] + wn * mean + pb;
    s_h[i] = h;
  }
  __syncthreads();

  // radix-select the KSEL-th largest |h| (exact, MSB-first 8-bit digits)
  unsigned prefix = 0; int rem = KSEL;
  for (int byte = 3; byte >= 0; --byte) {
    const int sh = byte * 8;
    const unsigned himask = (byte == 3) ? 0u : (0xFFFFFFFFu << (sh + 8));
    for (int i = t; i < 256; i += 1024) s_hist[i] = 0;
    __syncthreads();
    for (int i = t; i < NNODES; i += 1024) {
      unsigned kk = __float_as_uint(fabsf(s_h[i]));
      if ((kk & himask) == prefix) atomicAdd(&s_hist[(kk >> sh) & 255], 1);
    }
    __syncthreads();
    if (t == 0) {
      int cum = 0, d = 255;
      for (; d >= 0; --d) {
        int c = s_hist[d];
        if (cum + c >= rem) break;
        cum += c;
      }
      if (d < 0) d = 0;
      s_pfx = prefix | ((unsigned)d << sh);
      s_rem = rem - cum;
    }
    __syncthreads();
    prefix = s_pfx; rem = s_rem;
    __syncthreads();
  }
  const unsigned T = prefix;
  const int needed = rem;

  // prefix-rank over ==T elements (lowest-index tie-break, matches jax top_k)
  const int CH = 10;
  int i0 = t * CH;
  int i1 = i0 + CH; if (i1 > NNODES) i1 = NNODES;
  int loc = 0;
  for (int i = i0; i < i1; ++i)
    loc += (__float_as_uint(fabsf(s_h[i])) == T) ? 1 : 0;
  s_cnt[t] = loc;
  __syncthreads();
  for (int off = 1; off < 1024; off <<= 1) {
    int v = (t >= off) ? s_cnt[t - off] : 0;
    __syncthreads();
    s_cnt[t] += v;
    __syncthreads();
  }
  int rank = s_cnt[t] - loc;

  float a0 = 0.f, a1 = 0.f;
  for (int i = i0; i < i1; ++i) {
    float h = s_h[i];
    unsigned kk = __float_as_uint(fabsf(h));
    bool inc = false;
    if (kk > T) inc = true;
    else if (kk == T) { inc = (rank < needed); ++rank; }
    if (inc) {
      a0 += h * fc2w[i];
      a1 += h * fc2w[NNODES + i];
    }
  }
  s_red[t] = a0; __syncthreads();
  for (int off = 512; off > 0; off >>= 1) {
    if (t < off) s_red[t] += s_red[t + off];
    __syncthreads();
  }
  float r0 = s_red[0];
  __syncthreads();
  s_red[t] = a1; __syncthreads();
  for (int off = 512; off > 0; off >>= 1) {
    if (t < off) s_red[t] += s_red[t + off];
    __syncthreads();
  }
  if (t == 0) {
    out[g * 2 + 0] = r0 + fc2b[0];
    out[g * 2 + 1] = s_red[0] + fc2b[1];
  }
}

// ---------------- launch ----------------
extern "C" void kernel_launch(void* const* d_in, const int* in_sizes, int n_in,
                              void* d_out, int out_size, void* d_ws, size_t ws_size,
                              hipStream_t stream) {
  const float* tr  = (const float*)d_in[0];
  const float* x   = (const float*)d_in[1];
  const int*   ei  = (const int*)d_in[2];
  const float* adj = (const float*)d_in[4];
  const float* w1  = (const float*)d_in[5];
  const float* b1  = (const float*)d_in[6];
  const float* wr  = (const float*)d_in[7];
  const float* wn  = (const float*)d_in[8];
  const float* pb  = (const float*)d_in[9];
  const float* w2  = (const float*)d_in[10];
  const float* b2  = (const float*)d_in[11];

  char* ws = (char*)d_ws;
  float* xg = (float*)ws;                                   // 2.56 MB
  float* partials = (float*)(ws + (size_t)NTOT * 4 + 256);  // 32.8 MB
  size_t need = (size_t)NTOT * 4 + 256 + (size_t)KSPLIT * 64 * NANNOT * 4;
  const bool det = ws_size >= need;

  float* out = (float*)d_out;

  init_xg_kernel<<<(NTOT + 255) / 256, 256, 0, stream>>>(x, b1, xg);
  dim3 g1((NANNOT + ATILE - 1) / ATILE, KSPLIT);
  if (det) {
    fc1_kernel<1><<<g1, 256, 0, stream>>>(tr, w1, adj, xg, partials);
    reduce_kernel<<<(64 * NANNOT + 255) / 256, 256, 0, stream>>>(partials, b1, xg);
  } else {
    fc1_kernel<0><<<g1, 256, 0, stream>>>(tr, w1, adj, xg, partials);
  }
  graph_kernel<<<NGRAPH, 1024, 0, stream>>>(ei, xg, wr, wn, pb, w2, b2, out);
}

// Round 6
// 330.704 us; speedup vs baseline: 12.4908x; 1.4948x over previous
//
#include <hip/hip_runtime.h>
#include <hip/hip_bf16.h>

#define NGRAPH 64
#define NGENES 16000
#define NANNOT 8000
#define NNODES 10000
#define NTOT   (NGRAPH * NNODES)
#define DEG    4
#define NEDGE  (NGRAPH * NNODES * DEG)
#define KSEL   5000
#define FIXS   1048576.0f

#define KSPLIT 10
#define KSTEPS 50          // 1600 / 32 per block
#define LDSROW 40          // ushorts per LDS row: 32 + 8 pad (80 B, odd 16B-slot stride)

typedef __attribute__((ext_vector_type(8))) short bf16x8;
typedef __attribute__((ext_vector_type(4))) float f32x4;

__device__ __forceinline__ unsigned short f2bf(float x) {
  __hip_bfloat16 h = __float2bfloat16(x);            // RN
  return __builtin_bit_cast(unsigned short, h);
}
__device__ __forceinline__ float bf2f(unsigned short u) {
  unsigned int v = (unsigned int)u << 16;
  return __builtin_bit_cast(float, v);
}

// ---------------- kernel A: init xg = bias (annot) / x (rest) ----------------
__global__ void init_xg_kernel(const float* __restrict__ x,
                               const float* __restrict__ fc1_b,
                               float* __restrict__ xg) {
  int n = blockIdx.x * blockDim.x + threadIdx.x;
  if (n >= NTOT) return;
  int local = n % NNODES;
  xg[n] = (local < NANNOT) ? fc1_b[local] : x[n];
}

// ---------------- kernel B: masked fc1 via bf16x3 MFMA ----------------
// partials[ksp][64 b][8000 a] = tr[64 x kslice] * (w .* adj)^T[kslice x 8000]
// Block: 256 thr = 4 waves; tile M=64(b) x N=64(a), K-step 32, dbuf LDS.
__global__ __launch_bounds__(256, 1) void fc1_kernel(
    const float* __restrict__ tr, const float* __restrict__ w,
    const float* __restrict__ mk, float* __restrict__ partials) {
  __shared__ unsigned short sAh[2][64 * LDSROW];
  __shared__ unsigned short sAl[2][64 * LDSROW];
  __shared__ unsigned short sBh[2][64 * LDSROW];
  __shared__ unsigned short sBl[2][64 * LDSROW];

  const int t = threadIdx.x;
  const int abase = blockIdx.x * 64;                 // 125 blocks * 64 = 8000
  const int kbeg  = blockIdx.y * (NGENES / KSPLIT);  // 10 * 1600
  const int wv = t >> 6, lane = t & 63, lr = lane & 15, ls = lane >> 4;

  // staging coords: each thread owns 2 float4 per array (rows r0, r0+32)
  const int r0 = t >> 3, c0 = t & 7;
  const size_t gA0 = (size_t)r0 * NGENES + c0 * 4;
  const size_t gA1 = (size_t)(r0 + 32) * NGENES + c0 * 4;
  const size_t gB0 = (size_t)(abase + r0) * NGENES + c0 * 4;
  const size_t gB1 = (size_t)(abase + r0 + 32) * NGENES + c0 * 4;
  const int off0 = r0 * LDSROW + c0 * 4;
  const int off1 = (r0 + 32) * LDSROW + c0 * 4;

  float4 rt0, rt1, rw0, rw1, ra0, ra1;

  auto load_step = [&](int k0) {
    rt0 = *(const float4*)&tr[gA0 + k0];
    rt1 = *(const float4*)&tr[gA1 + k0];
    rw0 = *(const float4*)&w [gB0 + k0];
    rw1 = *(const float4*)&w [gB1 + k0];
    ra0 = *(const float4*)&mk[gB0 + k0];
    ra1 = *(const float4*)&mk[gB1 + k0];
  };
  auto cvt4 = [&](unsigned short* hp, unsigned short* lp, int off, float4 v) {
    ushort4 h, l;
    h.x = f2bf(v.x); l.x = f2bf(v.x - bf2f(h.x));
    h.y = f2bf(v.y); l.y = f2bf(v.y - bf2f(h.y));
    h.z = f2bf(v.z); l.z = f2bf(v.z - bf2f(h.z));
    h.w = f2bf(v.w); l.w = f2bf(v.w - bf2f(h.w));
    *(ushort4*)&hp[off] = h;
    *(ushort4*)&lp[off] = l;
  };
  auto store_step = [&](int buf) {
    cvt4(sAh[buf], sAl[buf], off0, rt0);
    cvt4(sAh[buf], sAl[buf], off1, rt1);
    float4 p0 = make_float4(rw0.x * ra0.x, rw0.y * ra0.y, rw0.z * ra0.z, rw0.w * ra0.w);
    float4 p1 = make_float4(rw1.x * ra1.x, rw1.y * ra1.y, rw1.z * ra1.z, rw1.w * ra1.w);
    cvt4(sBh[buf], sBl[buf], off0, p0);
    cvt4(sBh[buf], sBl[buf], off1, p1);
  };

  f32x4 acc[4];
#pragma unroll
  for (int mt = 0; mt < 4; ++mt)
#pragma unroll
    for (int r = 0; r < 4; ++r) acc[mt][r] = 0.f;

  load_step(kbeg);
  store_step(0);
  __syncthreads();

  const int fbA = lr * LDSROW + ls * 8;               // A row lr (+mt*16), k-block ls
  const int fbB = (wv * 16 + lr) * LDSROW + ls * 8;   // B col = wave's 16-col slice

#pragma unroll 1
  for (int s = 0; s < KSTEPS; ++s) {
    const int buf = s & 1;
    if (s + 1 < KSTEPS) load_step(kbeg + (s + 1) * 32);
    bf16x8 bh = *(const bf16x8*)&sBh[buf][fbB];
    bf16x8 bl = *(const bf16x8*)&sBl[buf][fbB];
#pragma unroll
    for (int mt = 0; mt < 4; ++mt) {
      bf16x8 ah = *(const bf16x8*)&sAh[buf][mt * 16 * LDSROW + fbA];
      bf16x8 al = *(const bf16x8*)&sAl[buf][mt * 16 * LDSROW + fbA];
      acc[mt] = __builtin_amdgcn_mfma_f32_16x16x32_bf16(ah, bh, acc[mt], 0, 0, 0);
      acc[mt] = __builtin_amdgcn_mfma_f32_16x16x32_bf16(ah, bl, acc[mt], 0, 0, 0);
      acc[mt] = __builtin_amdgcn_mfma_f32_16x16x32_bf16(al, bh, acc[mt], 0, 0, 0);
    }
    if (s + 1 < KSTEPS) store_step(buf ^ 1);
    __syncthreads();
  }

  // epilogue: D col = lane&15, row = (lane>>4)*4 + reg   [m89-verified]
  float* P = partials + (size_t)blockIdx.y * (64 * NANNOT);
  const int acol = abase + wv * 16 + lr;
#pragma unroll
  for (int mt = 0; mt < 4; ++mt) {
#pragma unroll
    for (int r = 0; r < 4; ++r) {
      int b = mt * 16 + ls * 4 + r;
      P[(size_t)b * NANNOT + acol] = acc[mt][r];
    }
  }
}

// ---------------- kernel B2: deterministic reduce of k-split partials --------
__global__ void reduce_kernel(const float* __restrict__ partials,
                              const float* __restrict__ fc1_b,
                              float* __restrict__ xg) {
  int idx = blockIdx.x * blockDim.x + threadIdx.x;
  if (idx >= 64 * NANNOT) return;
  int b = idx / NANNOT, a = idx % NANNOT;
  float s = fc1_b[a];
#pragma unroll
  for (int sp = 0; sp < KSPLIT; ++sp) s += partials[(size_t)sp * (64 * NANNOT) + idx];
  xg[(size_t)b * NNODES + a] = s;
}

// ---------------- kernel C: fused graph-conv + top-k + fc2 (unchanged) ------
__global__ __launch_bounds__(1024) void graph_kernel(
    const int* __restrict__ ei, const float* __restrict__ xg,
    const float* __restrict__ wrp, const float* __restrict__ wnp,
    const float* __restrict__ pbp, const float* __restrict__ fc2w,
    const float* __restrict__ fc2b, float* __restrict__ out) {
  const int g = blockIdx.x;
  const int t = threadIdx.x;
  __shared__ int   s_sum[NNODES];
  __shared__ int   s_deg[NNODES];
  __shared__ float s_h[NNODES];
  __shared__ int s_hist[256];
  __shared__ int s_cnt[1024];
  __shared__ float s_red[1024];
  __shared__ unsigned s_pfx;
  __shared__ int s_rem;

  for (int i = t; i < NNODES; i += 1024) { s_sum[i] = 0; s_deg[i] = 0; }
  __syncthreads();

  const int e0 = g * (NNODES * DEG);
  const int base = g * NNODES;
  for (int e = t; e < NNODES * DEG; e += 1024) {
    int s = ei[e0 + e];
    int d = ei[NEDGE + e0 + e];
    float v = ((unsigned)s < (unsigned)NTOT) ? xg[s] : 0.f;
    unsigned dl = (unsigned)(d - base);
    if (dl < (unsigned)NNODES) {
      atomicAdd(&s_sum[dl], __float2int_rn(v * FIXS));
      atomicAdd(&s_deg[dl], 1);
    }
  }
  __syncthreads();

  const float wr = wrp[0], wn = wnp[0], pb = pbp[0];
  for (int i = t; i < NNODES; i += 1024) {
    int dg = s_deg[i];
    float mean = ((float)s_sum[i] * (1.0f / FIXS)) / (float)(dg > 0 ? dg : 1);
    float h = wr * xg[base + i] + wn * mean + pb;
    s_h[i] = h;
  }
  __syncthreads();

  unsigned prefix = 0; int rem = KSEL;
  for (int byte = 3; byte >= 0; --byte) {
    const int sh = byte * 8;
    const unsigned himask = (byte == 3) ? 0u : (0xFFFFFFFFu << (sh + 8));
    for (int i = t; i < 256; i += 1024) s_hist[i] = 0;
    __syncthreads();
    for (int i = t; i < NNODES; i += 1024) {
      unsigned kk = __float_as_uint(fabsf(s_h[i]));
      if ((kk & himask) == prefix) atomicAdd(&s_hist[(kk >> sh) & 255], 1);
    }
    __syncthreads();
    if (t == 0) {
      int cum = 0, d = 255;
      for (; d >= 0; --d) {
        int c = s_hist[d];
        if (cum + c >= rem) break;
        cum += c;
      }
      if (d < 0) d = 0;
      s_pfx = prefix | ((unsigned)d << sh);
      s_rem = rem - cum;
    }
    __syncthreads();
    prefix = s_pfx; rem = s_rem;
    __syncthreads();
  }
  const unsigned T = prefix;
  const int needed = rem;

  const int CH = 10;
  int i0 = t * CH;
  int i1 = i0 + CH; if (i1 > NNODES) i1 = NNODES;
  int loc = 0;
  for (int i = i0; i < i1; ++i)
    loc += (__float_as_uint(fabsf(s_h[i])) == T) ? 1 : 0;
  s_cnt[t] = loc;
  __syncthreads();
  for (int off = 1; off < 1024; off <<= 1) {
    int v = (t >= off) ? s_cnt[t - off] : 0;
    __syncthreads();
    s_cnt[t] += v;
    __syncthreads();
  }
  int rank = s_cnt[t] - loc;

  float a0 = 0.f, a1 = 0.f;
  for (int i = i0; i < i1; ++i) {
    float h = s_h[i];
    unsigned kk = __float_as_uint(fabsf(h));
    bool inc = false;
    if (kk > T) inc = true;
    else if (kk == T) { inc = (rank < needed); ++rank; }
    if (inc) {
      a0 += h * fc2w[i];
      a1 += h * fc2w[NNODES + i];
    }
  }
  s_red[t] = a0; __syncthreads();
  for (int off = 512; off > 0; off >>= 1) {
    if (t < off) s_red[t] += s_red[t + off];
    __syncthreads();
  }
  float r0 = s_red[0];
  __syncthreads();
  s_red[t] = a1; __syncthreads();
  for (int off = 512; off > 0; off >>= 1) {
    if (t < off) s_red[t] += s_red[t + off];
    __syncthreads();
  }
  if (t == 0) {
    out[g * 2 + 0] = r0 + fc2b[0];
    out[g * 2 + 1] = s_red[0] + fc2b[1];
  }
}

// ---------------- launch ----------------
extern "C" void kernel_launch(void* const* d_in, const int* in_sizes, int n_in,
                              void* d_out, int out_size, void* d_ws, size_t ws_size,
                              hipStream_t stream) {
  const float* tr  = (const float*)d_in[0];
  const float* x   = (const float*)d_in[1];
  const int*   ei  = (const int*)d_in[2];
  const float* adj = (const float*)d_in[4];
  const float* w1  = (const float*)d_in[5];
  const float* b1  = (const float*)d_in[6];
  const float* wr  = (const float*)d_in[7];
  const float* wn  = (const float*)d_in[8];
  const float* pb  = (const float*)d_in[9];
  const float* w2  = (const float*)d_in[10];
  const float* b2  = (const float*)d_in[11];

  char* ws = (char*)d_ws;
  float* xg = (float*)ws;                                   // 2.56 MB
  float* partials = (float*)(ws + (size_t)NTOT * 4 + 256);  // 10*64*8000*4 = 20.5 MB
  float* out = (float*)d_out;

  init_xg_kernel<<<(NTOT + 255) / 256, 256, 0, stream>>>(x, b1, xg);
  dim3 g1(NANNOT / 64, KSPLIT);   // 125 x 10
  fc1_kernel<<<g1, 256, 0, stream>>>(tr, w1, adj, partials);
  reduce_kernel<<<(64 * NANNOT + 255) / 256, 256, 0, stream>>>(partials, b1, xg);
  graph_kernel<<<NGRAPH, 1024, 0, stream>>>(ei, xg, wr, wn, pb, w2, b2, out);
}

// Round 7
// 322.538 us; speedup vs baseline: 12.8070x; 1.0253x over previous
//
#include <hip/hip_runtime.h>
#include <hip/hip_bf16.h>

#define NGRAPH 64
#define NGENES 16000
#define NANNOT 8000
#define NNODES 10000
#define NTOT   (NGRAPH * NNODES)
#define DEG    4
#define NEDGE  (NGRAPH * NNODES * DEG)
#define KSEL   5000
#define FIXS   1048576.0f

#define KSPLIT 10
#define KSTEPS 50          // 1600 / 32 per block
#define LDSROW 36          // ushorts per row: 32 + 4 pad (72 B); total LDS 36864 B -> 4 blocks/CU

typedef __attribute__((ext_vector_type(8))) short bf16x8;
typedef __attribute__((ext_vector_type(4))) float f32x4;

__device__ __forceinline__ unsigned short f2bf(float x) {
  __hip_bfloat16 h = __float2bfloat16(x);            // RN
  return __builtin_bit_cast(unsigned short, h);
}
__device__ __forceinline__ float bf2f(unsigned short u) {
  unsigned int v = (unsigned int)u << 16;
  return __builtin_bit_cast(float, v);
}

// ---------------- kernel B: masked fc1 via bf16x3 MFMA ----------------
// partials[ksp][64 b][8000 a] = tr[64 x kslice] * (w .* adj)^T[kslice x 8000]
// 256 thr = 4 waves; tile M=64(b) x N=64(a), K-step 32, dbuf LDS, 2-deep prefetch.
__global__ __launch_bounds__(256, 4) void fc1_kernel(
    const float* __restrict__ tr, const float* __restrict__ w,
    const float* __restrict__ mk, float* __restrict__ partials) {
  __shared__ unsigned short sAh[2][64 * LDSROW];
  __shared__ unsigned short sAl[2][64 * LDSROW];
  __shared__ unsigned short sBh[2][64 * LDSROW];
  __shared__ unsigned short sBl[2][64 * LDSROW];

  const int t = threadIdx.x;
  const int abase = blockIdx.x * 64;                 // 125 blocks * 64 = 8000
  const int kbeg  = blockIdx.y * (NGENES / KSPLIT);  // 10 * 1600
  const int wv = t >> 6, lane = t & 63, lr = lane & 15, ls = lane >> 4;

  // staging coords: each thread owns 2 float4 per array (rows r0, r0+32)
  const int r0 = t >> 3, c0 = t & 7;
  const size_t gA0 = (size_t)r0 * NGENES + c0 * 4;
  const size_t gA1 = (size_t)(r0 + 32) * NGENES + c0 * 4;
  const size_t gB0 = (size_t)(abase + r0) * NGENES + c0 * 4;
  const size_t gB1 = (size_t)(abase + r0 + 32) * NGENES + c0 * 4;
  const int off0 = r0 * LDSROW + c0 * 4;
  const int off1 = (r0 + 32) * LDSROW + c0 * 4;

  float4 rt0, rt1, rw0, rw1, ra0, ra1;

  auto load_step = [&](int k0) {
    rt0 = *(const float4*)&tr[gA0 + k0];
    rt1 = *(const float4*)&tr[gA1 + k0];
    rw0 = *(const float4*)&w [gB0 + k0];
    rw1 = *(const float4*)&w [gB1 + k0];
    ra0 = *(const float4*)&mk[gB0 + k0];
    ra1 = *(const float4*)&mk[gB1 + k0];
  };
  auto cvt4 = [&](unsigned short* hp, unsigned short* lp, int off, float4 v) {
    ushort4 h, l;
    h.x = f2bf(v.x); l.x = f2bf(v.x - bf2f(h.x));
    h.y = f2bf(v.y); l.y = f2bf(v.y - bf2f(h.y));
    h.z = f2bf(v.z); l.z = f2bf(v.z - bf2f(h.z));
    h.w = f2bf(v.w); l.w = f2bf(v.w - bf2f(h.w));
    *(ushort4*)&hp[off] = h;
    *(ushort4*)&lp[off] = l;
  };
  auto store_step = [&](int buf) {
    cvt4(sAh[buf], sAl[buf], off0, rt0);
    cvt4(sAh[buf], sAl[buf], off1, rt1);
    float4 p0 = make_float4(rw0.x * ra0.x, rw0.y * ra0.y, rw0.z * ra0.z, rw0.w * ra0.w);
    float4 p1 = make_float4(rw1.x * ra1.x, rw1.y * ra1.y, rw1.z * ra1.z, rw1.w * ra1.w);
    cvt4(sBh[buf], sBl[buf], off0, p0);
    cvt4(sBh[buf], sBl[buf], off1, p1);
  };

  f32x4 acc[4];
#pragma unroll
  for (int mt = 0; mt < 4; ++mt)
#pragma unroll
    for (int r = 0; r < 4; ++r) acc[mt][r] = 0.f;

  // prologue: fill buf0, then issue loads for step 1 before the barrier
  load_step(kbeg);
  store_step(0);
  load_step(kbeg + 32);
  __syncthreads();

  const int fbA = lr * LDSROW + ls * 8;               // A row lr (+mt*16), k-block ls
  const int fbB = (wv * 16 + lr) * LDSROW + ls * 8;   // B col = wave's 16-col slice

#pragma unroll 1
  for (int s = 0; s < KSTEPS; ++s) {
    const int buf = s & 1;
    bf16x8 bh = *(const bf16x8*)&sBh[buf][fbB];
    bf16x8 bl = *(const bf16x8*)&sBl[buf][fbB];
#pragma unroll
    for (int mt = 0; mt < 4; ++mt) {
      bf16x8 ah = *(const bf16x8*)&sAh[buf][mt * 16 * LDSROW + fbA];
      bf16x8 al = *(const bf16x8*)&sAl[buf][mt * 16 * LDSROW + fbA];
      acc[mt] = __builtin_amdgcn_mfma_f32_16x16x32_bf16(ah, bh, acc[mt], 0, 0, 0);
      acc[mt] = __builtin_amdgcn_mfma_f32_16x16x32_bf16(ah, bl, acc[mt], 0, 0, 0);
      acc[mt] = __builtin_amdgcn_mfma_f32_16x16x32_bf16(al, bh, acc[mt], 0, 0, 0);
    }
    // tail: commit regs (step s+1) to LDS, then refill regs for step s+2 —
    // gives the global loads a full iteration (barrier + MFMA) to land
    if (s + 1 < KSTEPS) {
      store_step(buf ^ 1);
      if (s + 2 < KSTEPS) load_step(kbeg + (s + 2) * 32);
    }
    __syncthreads();
  }

  // epilogue: D col = lane&15, row = (lane>>4)*4 + reg   [m89-verified]
  float* P = partials + (size_t)blockIdx.y * (64 * NANNOT);
  const int acol = abase + wv * 16 + lr;
#pragma unroll
  for (int mt = 0; mt < 4; ++mt) {
#pragma unroll
    for (int r = 0; r < 4; ++r) {
      int b = mt * 16 + ls * 4 + r;
      P[(size_t)b * NANNOT + acol] = acc[mt][r];
    }
  }
}

// ---------------- kernel B2: finalize xg (init + deterministic k-split reduce) -----
__global__ void finalize_kernel(const float* __restrict__ partials,
                                const float* __restrict__ fc1_b,
                                const float* __restrict__ x,
                                float* __restrict__ xg) {
  int idx = blockIdx.x * blockDim.x + threadIdx.x;
  if (idx >= NTOT) return;
  int b = idx / NNODES, local = idx % NNODES;
  float s;
  if (local < NANNOT) {
    s = fc1_b[local];
    int pidx = b * NANNOT + local;
#pragma unroll
    for (int sp = 0; sp < KSPLIT; ++sp) s += partials[(size_t)sp * (64 * NANNOT) + pidx];
  } else {
    s = x[idx];
  }
  xg[idx] = s;
}

// ---------------- kernel C: fused graph-conv + top-k + fc2 ------------------
__global__ __launch_bounds__(1024) void graph_kernel(
    const int* __restrict__ ei, const float* __restrict__ xg,
    const float* __restrict__ wrp, const float* __restrict__ wnp,
    const float* __restrict__ pbp, const float* __restrict__ fc2w,
    const float* __restrict__ fc2b, float* __restrict__ out) {
  const int g = blockIdx.x;
  const int t = threadIdx.x;
  __shared__ int   s_sum[NNODES];
  __shared__ int   s_deg[NNODES];
  __shared__ float s_h[NNODES];
  __shared__ int s_hist[256];
  __shared__ int s_cnt[1024];
  __shared__ float s_red[1024];
  __shared__ unsigned s_pfx;
  __shared__ int s_rem;

  for (int i = t; i < NNODES; i += 1024) { s_sum[i] = 0; s_deg[i] = 0; }
  __syncthreads();

  const int e0 = g * (NNODES * DEG);
  const int base = g * NNODES;
  for (int e = t; e < NNODES * DEG; e += 1024) {
    int s = ei[e0 + e];
    int d = ei[NEDGE + e0 + e];
    float v = ((unsigned)s < (unsigned)NTOT) ? xg[s] : 0.f;
    unsigned dl = (unsigned)(d - base);
    if (dl < (unsigned)NNODES) {
      atomicAdd(&s_sum[dl], __float2int_rn(v * FIXS));
      atomicAdd(&s_deg[dl], 1);
    }
  }
  __syncthreads();

  const float wr = wrp[0], wn = wnp[0], pb = pbp[0];
  for (int i = t; i < NNODES; i += 1024) {
    int dg = s_deg[i];
    float mean = ((float)s_sum[i] * (1.0f / FIXS)) / (float)(dg > 0 ? dg : 1);
    float h = wr * xg[base + i] + wn * mean + pb;
    s_h[i] = h;
  }
  __syncthreads();

  unsigned prefix = 0; int rem = KSEL;
  for (int byte = 3; byte >= 0; --byte) {
    const int sh = byte * 8;
    const unsigned himask = (byte == 3) ? 0u : (0xFFFFFFFFu << (sh + 8));
    for (int i = t; i < 256; i += 1024) s_hist[i] = 0;
    __syncthreads();
    for (int i = t; i < NNODES; i += 1024) {
      unsigned kk = __float_as_uint(fabsf(s_h[i]));
      if ((kk & himask) == prefix) atomicAdd(&s_hist[(kk >> sh) & 255], 1);
    }
    __syncthreads();
    if (t == 0) {
      int cum = 0, d = 255;
      for (; d >= 0; --d) {
        int c = s_hist[d];
        if (cum + c >= rem) break;
        cum += c;
      }
      if (d < 0) d = 0;
      s_pfx = prefix | ((unsigned)d << sh);
      s_rem = rem - cum;
    }
    __syncthreads();
    prefix = s_pfx; rem = s_rem;
    __syncthreads();
  }
  const unsigned T = prefix;
  const int needed = rem;

  const int CH = 10;
  int i0 = t * CH;
  int i1 = i0 + CH; if (i1 > NNODES) i1 = NNODES;
  int loc = 0;
  for (int i = i0; i < i1; ++i)
    loc += (__float_as_uint(fabsf(s_h[i])) == T) ? 1 : 0;
  s_cnt[t] = loc;
  __syncthreads();
  for (int off = 1; off < 1024; off <<= 1) {
    int v = (t >= off) ? s_cnt[t - off] : 0;
    __syncthreads();
    s_cnt[t] += v;
    __syncthreads();
  }
  int rank = s_cnt[t] - loc;

  float a0 = 0.f, a1 = 0.f;
  for (int i = i0; i < i1; ++i) {
    float h = s_h[i];
    unsigned kk = __float_as_uint(fabsf(h));
    bool inc = false;
    if (kk > T) inc = true;
    else if (kk == T) { inc = (rank < needed); ++rank; }
    if (inc) {
      a0 += h * fc2w[i];
      a1 += h * fc2w[NNODES + i];
    }
  }
  s_red[t] = a0; __syncthreads();
  for (int off = 512; off > 0; off >>= 1) {
    if (t < off) s_red[t] += s_red[t + off];
    __syncthreads();
  }
  float r0 = s_red[0];
  __syncthreads();
  s_red[t] = a1; __syncthreads();
  for (int off = 512; off > 0; off >>= 1) {
    if (t < off) s_red[t] += s_red[t + off];
    __syncthreads();
  }
  if (t == 0) {
    out[g * 2 + 0] = r0 + fc2b[0];
    out[g * 2 + 1] = s_red[0] + fc2b[1];
  }
}

// ---------------- launch ----------------
extern "C" void kernel_launch(void* const* d_in, const int* in_sizes, int n_in,
                              void* d_out, int out_size, void* d_ws, size_t ws_size,
                              hipStream_t stream) {
  const float* tr  = (const float*)d_in[0];
  const float* x   = (const float*)d_in[1];
  const int*   ei  = (const int*)d_in[2];
  const float* adj = (const float*)d_in[4];
  const float* w1  = (const float*)d_in[5];
  const float* b1  = (const float*)d_in[6];
  const float* wr  = (const float*)d_in[7];
  const float* wn  = (const float*)d_in[8];
  const float* pb  = (const float*)d_in[9];
  const float* w2  = (const float*)d_in[10];
  const float* b2  = (const float*)d_in[11];

  char* ws = (char*)d_ws;
  float* xg = (float*)ws;                                   // 2.56 MB
  float* partials = (float*)(ws + (size_t)NTOT * 4 + 256);  // 10*64*8000*4 = 20.5 MB
  float* out = (float*)d_out;

  dim3 g1(NANNOT / 64, KSPLIT);   // 125 x 10
  fc1_kernel<<<g1, 256, 0, stream>>>(tr, w1, adj, partials);
  finalize_kernel<<<(NTOT + 255) / 256, 256, 0, stream>>>(partials, b1, x, xg);
  graph_kernel<<<NGRAPH, 1024, 0, stream>>>(ei, xg, wr, wn, pb, w2, b2, out);
}

// Round 8
// 277.810 us; speedup vs baseline: 14.8689x; 1.1610x over previous
//
#include <hip/hip_runtime.h>
#include <hip/hip_bf16.h>

#define NGRAPH 64
#define NGENES 16000
#define NANNOT 8000
#define NNODES 10000
#define NTOT   (NGRAPH * NNODES)
#define DEG    4
#define NEDGE  (NGRAPH * NNODES * DEG)
#define KSEL   5000
#define FIXS   1048576.0f

#define KSPLIT 2
#define KSTEP  64
#define KSTEPS (NGENES / KSPLIT / KSTEP)   // 125
#define LDSROW 68                          // 64 + 4 pad ushorts (136 B row; dword stride 34 == 2 mod 32 -> 2-way max, free)

typedef __attribute__((ext_vector_type(8))) short bf16x8;
typedef __attribute__((ext_vector_type(4))) float f32x4;

__device__ __forceinline__ unsigned short f2bf(float x) {
  __hip_bfloat16 h = __float2bfloat16(x);            // RN
  return __builtin_bit_cast(unsigned short, h);
}
__device__ __forceinline__ float bf2f(unsigned short u) {
  unsigned int v = (unsigned int)u << 16;
  return __builtin_bit_cast(float, v);
}

// ---------------- kernel B: masked fc1 via bf16x3 MFMA, coarse-stream edition -------
// partials[ksp][64 b][8000 a] = tr[64 x kslice] * (w .* adj)^T[kslice x 8000]
// 256 thr = 4 waves; tile M=64(b) x N=64(a), K-step 64, dbuf LDS, 2-deep prefetch.
// KSPLIT=2 -> 250 blocks fully resident; 256B contiguous per row per step.
__global__ __launch_bounds__(256, 1) void fc1_kernel(
    const float* __restrict__ tr, const float* __restrict__ w,
    const float* __restrict__ mk, float* __restrict__ partials) {
  __shared__ unsigned short sAh[2][64 * LDSROW];
  __shared__ unsigned short sAl[2][64 * LDSROW];
  __shared__ unsigned short sBh[2][64 * LDSROW];
  __shared__ unsigned short sBl[2][64 * LDSROW];

  const int t = threadIdx.x;
  const int abase = blockIdx.x * 64;                 // 125 * 64 = 8000
  const int kbeg  = blockIdx.y * (NGENES / KSPLIT);  // 0 or 8000
  const int wv = t >> 6, lane = t & 63, lr = lane & 15, ls = lane >> 4;

  // staging: thread owns 4 rows (r0+16p), one float4 (c0) per 64-float row chunk
  const int r0 = t >> 4, c0 = t & 15;
  size_t gT[4], gB[4];
  int offL[4];
#pragma unroll
  for (int p = 0; p < 4; ++p) {
    int row = r0 + 16 * p;
    gT[p] = (size_t)row * NGENES + c0 * 4;
    gB[p] = (size_t)(abase + row) * NGENES + c0 * 4;
    offL[p] = row * LDSROW + c0 * 4;
  }

  float4 rt[4], rw[4], ra[4];

  auto load_step = [&](int k0) {
#pragma unroll
    for (int p = 0; p < 4; ++p) {
      rt[p] = *(const float4*)&tr[gT[p] + k0];
      rw[p] = *(const float4*)&w [gB[p] + k0];
      ra[p] = *(const float4*)&mk[gB[p] + k0];
    }
  };
  auto cvt4 = [&](unsigned short* hp, unsigned short* lp, int off, float4 v) {
    ushort4 h, l;
    h.x = f2bf(v.x); l.x = f2bf(v.x - bf2f(h.x));
    h.y = f2bf(v.y); l.y = f2bf(v.y - bf2f(h.y));
    h.z = f2bf(v.z); l.z = f2bf(v.z - bf2f(h.z));
    h.w = f2bf(v.w); l.w = f2bf(v.w - bf2f(h.w));
    *(ushort4*)&hp[off] = h;
    *(ushort4*)&lp[off] = l;
  };
  auto store_step = [&](int buf) {
#pragma unroll
    for (int p = 0; p < 4; ++p) {
      cvt4(sAh[buf], sAl[buf], offL[p], rt[p]);
      float4 pr = make_float4(rw[p].x * ra[p].x, rw[p].y * ra[p].y,
                              rw[p].z * ra[p].z, rw[p].w * ra[p].w);
      cvt4(sBh[buf], sBl[buf], offL[p], pr);
    }
  };

  f32x4 acc[4];
#pragma unroll
  for (int mt = 0; mt < 4; ++mt)
#pragma unroll
    for (int r = 0; r < 4; ++r) acc[mt][r] = 0.f;

  load_step(kbeg);
  store_step(0);
  load_step(kbeg + KSTEP);
  __syncthreads();

  const int fbA = lr * LDSROW + ls * 8;
  const int fbB = (wv * 16 + lr) * LDSROW + ls * 8;

#pragma unroll 1
  for (int s = 0; s < KSTEPS; ++s) {
    const int buf = s & 1;
#pragma unroll
    for (int ks = 0; ks < 2; ++ks) {
      bf16x8 bh = *(const bf16x8*)&sBh[buf][fbB + ks * 32];
      bf16x8 bl = *(const bf16x8*)&sBl[buf][fbB + ks * 32];
#pragma unroll
      for (int mt = 0; mt < 4; ++mt) {
        bf16x8 ah = *(const bf16x8*)&sAh[buf][mt * 16 * LDSROW + fbA + ks * 32];
        bf16x8 al = *(const bf16x8*)&sAl[buf][mt * 16 * LDSROW + fbA + ks * 32];
        acc[mt] = __builtin_amdgcn_mfma_f32_16x16x32_bf16(ah, bh, acc[mt], 0, 0, 0);
        acc[mt] = __builtin_amdgcn_mfma_f32_16x16x32_bf16(ah, bl, acc[mt], 0, 0, 0);
        acc[mt] = __builtin_amdgcn_mfma_f32_16x16x32_bf16(al, bh, acc[mt], 0, 0, 0);
      }
    }
    if (s + 1 < KSTEPS) {
      store_step(buf ^ 1);
      if (s + 2 < KSTEPS) load_step(kbeg + (s + 2) * KSTEP);
    }
    __syncthreads();
  }

  // epilogue: D col = lane&15, row = (lane>>4)*4 + reg   [m89-verified]
  float* P = partials + (size_t)blockIdx.y * (64 * NANNOT);
  const int acol = abase + wv * 16 + lr;
#pragma unroll
  for (int mt = 0; mt < 4; ++mt) {
#pragma unroll
    for (int r = 0; r < 4; ++r) {
      int b = mt * 16 + ls * 4 + r;
      P[(size_t)b * NANNOT + acol] = acc[mt][r];
    }
  }
}

// ---------------- kernel B2: finalize xg (init + deterministic k-split reduce) -----
__global__ void finalize_kernel(const float* __restrict__ partials,
                                const float* __restrict__ fc1_b,
                                const float* __restrict__ x,
                                float* __restrict__ xg) {
  int idx = blockIdx.x * blockDim.x + threadIdx.x;
  if (idx >= NTOT) return;
  int b = idx / NNODES, local = idx % NNODES;
  float s;
  if (local < NANNOT) {
    s = fc1_b[local];
    int pidx = b * NANNOT + local;
#pragma unroll
    for (int sp = 0; sp < KSPLIT; ++sp) s += partials[(size_t)sp * (64 * NANNOT) + pidx];
  } else {
    s = x[idx];
  }
  xg[idx] = s;
}

// ---------------- kernel C: fused graph-conv + top-k + fc2 ------------------
__global__ __launch_bounds__(1024) void graph_kernel(
    const int* __restrict__ ei, const float* __restrict__ xg,
    const float* __restrict__ wrp, const float* __restrict__ wnp,
    const float* __restrict__ pbp, const float* __restrict__ fc2w,
    const float* __restrict__ fc2b, float* __restrict__ out) {
  const int g = blockIdx.x;
  const int t = threadIdx.x;
  __shared__ int   s_sum[NNODES];
  __shared__ int   s_deg[NNODES];
  __shared__ float s_h[NNODES];
  __shared__ int s_hist[256];
  __shared__ int s_cnt[1024];
  __shared__ float s_red[1024];
  __shared__ unsigned s_pfx;
  __shared__ int s_rem;

  for (int i = t; i < NNODES; i += 1024) { s_sum[i] = 0; s_deg[i] = 0; }
  __syncthreads();

  const int e0 = g * (NNODES * DEG);
  const int base = g * NNODES;
  // vectorized edge loop: 4 edges per int4
  const int4* src4 = (const int4*)(ei + e0);
  const int4* dst4 = (const int4*)(ei + NEDGE + e0);
  for (int q = t; q < (NNODES * DEG) / 4; q += 1024) {
    int4 s4 = src4[q];
    int4 d4 = dst4[q];
#pragma unroll
    for (int u = 0; u < 4; ++u) {
      int s = (&s4.x)[u];
      int d = (&d4.x)[u];
      float v = ((unsigned)s < (unsigned)NTOT) ? xg[s] : 0.f;
      unsigned dl = (unsigned)(d - base);
      if (dl < (unsigned)NNODES) {
        atomicAdd(&s_sum[dl], __float2int_rn(v * FIXS));
        atomicAdd(&s_deg[dl], 1);
      }
    }
  }
  __syncthreads();

  const float wr = wrp[0], wn = wnp[0], pb = pbp[0];
  for (int i = t; i < NNODES; i += 1024) {
    int dg = s_deg[i];
    float mean = ((float)s_sum[i] * (1.0f / FIXS)) / (float)(dg > 0 ? dg : 1);
    float h = wr * xg[base + i] + wn * mean + pb;
    s_h[i] = h;
  }
  __syncthreads();

  // radix-select the KSEL-th largest |h|; digit chosen by parallel suffix-scan
  unsigned prefix = 0; int rem = KSEL;
  for (int byte = 3; byte >= 0; --byte) {
    const int sh = byte * 8;
    const unsigned himask = (byte == 3) ? 0u : (0xFFFFFFFFu << (sh + 8));
    if (t < 256) s_hist[t] = 0;
    __syncthreads();
    for (int i = t; i < NNODES; i += 1024) {
      unsigned kk = __float_as_uint(fabsf(s_h[i]));
      if ((kk & himask) == prefix) atomicAdd(&s_hist[(kk >> sh) & 255], 1);
    }
    __syncthreads();
    // suffix sums: s_cnt[d] = # matching keys with digit >= d
    if (t < 256) s_cnt[t] = s_hist[t];
    __syncthreads();
    for (int off = 1; off < 256; off <<= 1) {
      int v = 0;
      if (t < 256 && t + off < 256) v = s_cnt[t + off];
      __syncthreads();
      if (t < 256) s_cnt[t] += v;
      __syncthreads();
    }
    if (t < 256) {
      int ge = s_cnt[t];
      int ge_next = (t == 255) ? 0 : s_cnt[t + 1];
      if (ge >= rem && ge_next < rem) {      // exactly one t qualifies
        s_pfx = prefix | ((unsigned)t << sh);
        s_rem = rem - ge_next;
      }
    }
    __syncthreads();
    prefix = s_pfx; rem = s_rem;
    __syncthreads();
  }
  const unsigned T = prefix;
  const int needed = rem;

  // prefix-rank over ==T elements (lowest-index tie-break, matches jax top_k)
  const int CH = 10;
  int i0 = t * CH;
  int i1 = i0 + CH; if (i1 > NNODES) i1 = NNODES;
  int loc = 0;
  for (int i = i0; i < i1; ++i)
    loc += (__float_as_uint(fabsf(s_h[i])) == T) ? 1 : 0;
  s_cnt[t] = loc;
  __syncthreads();
  for (int off = 1; off < 1024; off <<= 1) {
    int v = (t >= off) ? s_cnt[t - off] : 0;
    __syncthreads();
    s_cnt[t] += v;
    __syncthreads();
  }
  int rank = s_cnt[t] - loc;

  float a0 = 0.f, a1 = 0.f;
  for (int i = i0; i < i1; ++i) {
    float h = s_h[i];
    unsigned kk = __float_as_uint(fabsf(h));
    bool inc = false;
    if (kk > T) inc = true;
    else if (kk == T) { inc = (rank < needed); ++rank; }
    if (inc) {
      a0 += h * fc2w[i];
      a1 += h * fc2w[NNODES + i];
    }
  }
  s_red[t] = a0; __syncthreads();
  for (int off = 512; off > 0; off >>= 1) {
    if (t < off) s_red[t] += s_red[t + off];
    __syncthreads();
  }
  float r0 = s_red[0];
  __syncthreads();
  s_red[t] = a1; __syncthreads();
  for (int off = 512; off > 0; off >>= 1) {
    if (t < off) s_red[t] += s_red[t + off];
    __syncthreads();
  }
  if (t == 0) {
    out[g * 2 + 0] = r0 + fc2b[0];
    out[g * 2 + 1] = s_red[0] + fc2b[1];
  }
}

// ---------------- launch ----------------
extern "C" void kernel_launch(void* const* d_in, const int* in_sizes, int n_in,
                              void* d_out, int out_size, void* d_ws, size_t ws_size,
                              hipStream_t stream) {
  const float* tr  = (const float*)d_in[0];
  const float* x   = (const float*)d_in[1];
  const int*   ei  = (const int*)d_in[2];
  const float* adj = (const float*)d_in[4];
  const float* w1  = (const float*)d_in[5];
  const float* b1  = (const float*)d_in[6];
  const float* wr  = (const float*)d_in[7];
  const float* wn  = (const float*)d_in[8];
  const float* pb  = (const float*)d_in[9];
  const float* w2  = (const float*)d_in[10];
  const float* b2  = (const float*)d_in[11];

  char* ws = (char*)d_ws;
  float* xg = (float*)ws;                                   // 2.56 MB
  float* partials = (float*)(ws + (size_t)NTOT * 4 + 256);  // 2*64*8000*4 = 4.1 MB
  float* out = (float*)d_out;

  dim3 g1(NANNOT / 64, KSPLIT);   // 125 x 2 = 250 blocks, fully resident
  fc1_kernel<<<g1, 256, 0, stream>>>(tr, w1, adj, partials);
  finalize_kernel<<<(NTOT + 255) / 256, 256, 0, stream>>>(partials, b1, x, xg);
  graph_kernel<<<NGRAPH, 1024, 0, stream>>>(ei, xg, wr, wn, pb, w2, b2, out);
}